// Round 8
// baseline (226.890 us; speedup 1.0000x reference)
//
#include <hip/hip_runtime.h>
#include <hip/hip_cooperative_groups.h>
#include <math.h>

namespace cg = cooperative_groups;

#define HWPIX 3136   // 56*56
#define NC    256
#define NCNEW 128
#define NH    16     // C/R
#define NBATCH 32
#define NBLK  512    // cooperative grid: 2 blocks/CU (LDS allows 3 -> co-residency safe)
#define NWAVE (NBLK * 4)

// ---------------------------------------------------------------------------
// numpy pairwise block sum (8 <= n <= 128) — exact np arithmetic order.
// ---------------------------------------------------------------------------
__device__ __forceinline__ float np_block_sum(const float* __restrict__ a, int n) {
    float r0=a[0],r1=a[1],r2=a[2],r3=a[3],r4=a[4],r5=a[5],r6=a[6],r7=a[7];
    int i = 8;
    const int lim = n - (n & 7);
    for (; i < lim; i += 8) {
        r0 += a[i+0]; r1 += a[i+1]; r2 += a[i+2]; r3 += a[i+3];
        r4 += a[i+4]; r5 += a[i+5]; r6 += a[i+6]; r7 += a[i+7];
    }
    float res = ((r0 + r1) + (r2 + r3)) + ((r4 + r5) + (r6 + r7));
    for (; i < n; ++i) res += a[i];
    return res;
}

// ---------------------------------------------------------------------------
// Fully fused SE layer as ONE cooperative kernel. Round-7 instrumentation
// showed per-graph-edge gaps of ~5-7us dominate (K+3g=43.7us, F=4.8us,
// model K~26us); fusing removes all inter-kernel edges.
//   phase 1: per-plane np.float32 mean (bit-exact), 4 planes/wave
//   phase 2: blocks 0..31 run the f32 MLP + sigmoid + exact stable rank
//   phase 3: gather+scale selected planes, 2 planes/wave
// ---------------------------------------------------------------------------
__global__ __launch_bounds__(256) void k_fused(const float* __restrict__ x,
                                               const float* __restrict__ w1,
                                               const float* __restrict__ b1,
                                               const float* __restrict__ w2,
                                               const float* __restrict__ b2,
                                               float* __restrict__ s_ws,
                                               float* __restrict__ gate_w,
                                               int* __restrict__ idx_w,
                                               float* __restrict__ out) {
    __shared__ float smem[4][HWPIX];   // 50176 B; reused by phase 2
    cg::grid_group grid = cg::this_grid();

    const int tid = threadIdx.x;
    const int w = tid >> 6;    // wave in block
    const int t = tid & 63;    // lane
    const int wave_id = blockIdx.x * 4 + w;

    // ---------------- phase 1: means (bit-exact np pairwise) ----------------
    float* pw = smem[w];
    #pragma unroll 1
    for (int it = 0; it < 4; ++it) {
        const int plane = wave_id + it * NWAVE;          // 0..8191 = b*256+c
        const float4* src4 = reinterpret_cast<const float4*>(
            x + (size_t)plane * HWPIX);

        float4 va[13];
        #pragma unroll
        for (int i = 0; i < 12; ++i) va[i] = src4[i * 64 + t];
        {   int idx = 768 + t; if (idx > 783) idx = 783;
            va[12] = src4[idx];
        }
        #pragma unroll
        for (int i = 0; i < 12; ++i)
            *reinterpret_cast<float4*>(&pw[(i * 64 + t) * 4]) = va[i];
        if (t < 16)
            *reinterpret_cast<float4*>(&pw[(768 + t) * 4]) = va[12];
        // wave-private LDS slab: in-wave ds ordering via lgkmcnt, no barrier

        const int m    = t >> 1;
        const int base = 98 * m + ((t & 1) ? 48 : 0);
        const int n    = (t & 1) ? 50 : 48;
        float v = np_block_sum(pw + base, n);

        #pragma unroll
        for (int mask = 1; mask <= 32; mask <<= 1)
            v += __shfl_xor(v, mask, 64);

        if (t == 0) s_ws[plane] = v / 3136.0f;
    }

    __threadfence();
    grid.sync();

    // ---------------- phase 2: MLP + sigmoid + exact stable rank ------------
    if (blockIdx.x < NBATCH) {
        const int b = blockIdx.x;
        float* sh_s   = &smem[0][0];        // 256
        float* sh_w1t = sh_s + NC;          // 4096, transposed [k][j] -> k*NH+j
        float* sh_w2  = sh_w1t + NC * NH;   // 4096, row-major [c][j]
        float* sh_h   = sh_w2 + NC * NH;    // 16
        float* sh_g   = sh_h + NH;          // 256

        const float bias2 = b2[tid];
        float bias1 = 0.0f;
        if (tid < NH) bias1 = b1[tid];

        #pragma unroll
        for (int i = 0; i < 4; ++i) {
            const int f4 = i * 256 + tid;
            float4 v = reinterpret_cast<const float4*>(w1)[f4];
            const int base = f4 * 4;        // flat = j*256 + k
            const int j = base >> 8;
            const int k = base & 255;
            sh_w1t[(k+0)*NH + j] = v.x; sh_w1t[(k+1)*NH + j] = v.y;
            sh_w1t[(k+2)*NH + j] = v.z; sh_w1t[(k+3)*NH + j] = v.w;
            reinterpret_cast<float4*>(sh_w2)[f4] =
                reinterpret_cast<const float4*>(w2)[f4];
        }
        if (tid < 64)
            reinterpret_cast<float4*>(sh_s)[tid] =
                reinterpret_cast<const float4*>(s_ws + b * NC)[tid];
        __syncthreads();

        if (tid < NH) {
            float acc = 0.0f;
            #pragma unroll 16
            for (int k = 0; k < NC; ++k)
                acc = fmaf(sh_s[k], sh_w1t[k*NH + tid], acc);  // exact seq-k
            float hp = acc + bias1;                            // bias after
            sh_h[tid] = fmaxf(hp, 0.0f);                       // relu
        }
        __syncthreads();

        float acc = 0.0f;
        #pragma unroll
        for (int j = 0; j < NH; ++j)
            acc = fmaf(sh_h[j], sh_w2[tid * NH + j], acc);
        const float z  = acc + bias2;
        const float ef = (float)exp((double)(-z));  // ~cr f32 exp
        const float g  = 1.0f / (1.0f + ef);
        sh_g[tid] = g;
        __syncthreads();

        int r = 0;
        #pragma unroll 8
        for (int k = 0; k < NC; ++k) {
            const float gk = sh_g[k];
            r += (gk > g) || (gk == g && k < tid);
        }
        if (r < NCNEW) {
            gate_w[b * NCNEW + r] = g;
            idx_w[b * NCNEW + r]  = tid;
        }
    }

    __threadfence();
    grid.sync();

    // ---------------- phase 3: gather + scale (bit-exact f32 mul) -----------
    #pragma unroll 1
    for (int it = 0; it < 2; ++it) {
        const int op = wave_id + it * NWAVE;    // 0..4095 = b*128 + j
        const int b = op >> 7;
        const int c = idx_w[op];
        const float g = gate_w[op];

        const float4* src = reinterpret_cast<const float4*>(
            x + ((size_t)(b * NC + c)) * HWPIX);
        float4* dst = reinterpret_cast<float4*>(out + (size_t)op * HWPIX);

        float4 va[13];
        #pragma unroll
        for (int i = 0; i < 12; ++i) va[i] = src[i * 64 + t];
        {   int ii = 768 + t; if (ii > 783) ii = 783;
            va[12] = src[ii];
        }
        #pragma unroll
        for (int i = 0; i < 12; ++i) {
            float4 v = va[i];
            v.x *= g; v.y *= g; v.z *= g; v.w *= g;
            dst[i * 64 + t] = v;
        }
        if (t < 16) {
            float4 v = va[12];
            v.x *= g; v.y *= g; v.z *= g; v.w *= g;
            dst[768 + t] = v;
        }
    }
}

// ---------------------------------------------------------------------------
extern "C" void kernel_launch(void* const* d_in, const int* in_sizes, int n_in,
                              void* d_out, int out_size, void* d_ws, size_t ws_size,
                              hipStream_t stream) {
    const float* x  = (const float*)d_in[0];
    const float* w1 = (const float*)d_in[1];
    const float* b1 = (const float*)d_in[2];
    const float* w2 = (const float*)d_in[3];
    const float* b2 = (const float*)d_in[4];
    float* out = (float*)d_out;

    char* ws = (char*)d_ws;
    float* s_ws   = (float*)ws;                     // 32768 B
    float* gate_w = (float*)(ws + 32768);           // 16384 B
    int*   idx_w  = (int*)(ws + 32768 + 16384);     // 16384 B

    void* args[] = {(void*)&x, (void*)&w1, (void*)&b1, (void*)&w2, (void*)&b2,
                    (void*)&s_ws, (void*)&gate_w, (void*)&idx_w, (void*)&out};
    hipLaunchCooperativeKernel((void*)k_fused, dim3(NBLK), dim3(256),
                               args, 0, stream);
}